// Round 5
// baseline (649.972 us; speedup 1.0000x reference)
//
#include <hip/hip_runtime.h>
#include <cstdint>
#include <cstddef>

// Problem constants
#define B_ROWS 16384
#define FEAT   2048
#define FIELD  32
#define KDIM   64
#define NCOLS  2048           // FIELD*KDIM (main quadratic columns)
#define NAUG   2176           // 2048 + 64 (vsum) + 1 (w) + 63 zero-pad = 17*128

using half8   = __attribute__((ext_vector_type(8))) _Float16;
using half4   = __attribute__((ext_vector_type(4))) _Float16;
using floatx4 = __attribute__((ext_vector_type(4))) float;

// Async global->LDS, 16B per lane. LDS dest must be wave-uniform base + lane*16.
__device__ __forceinline__ void load_lds16(const void* g, void* l) {
  __builtin_amdgcn_global_load_lds((const __attribute__((address_space(1))) void*)g,
                                   (__attribute__((address_space(3))) void*)l, 16, 0, 0);
}

// --- prep part 1: x fp32 -> xh fp16 (split out so rocprof times it) --------
__global__ __launch_bounds__(256) void k_prep_x(const float* __restrict__ x,
                                                _Float16* __restrict__ xh) {
  const int bb = blockIdx.x;
  const int t = threadIdx.x;
  size_t i = ((size_t)bb * 256 + t) * 16;
  float4 v0 = *(const float4*)(x + i);
  float4 v1 = *(const float4*)(x + i + 4);
  float4 v2 = *(const float4*)(x + i + 8);
  float4 v3 = *(const float4*)(x + i + 12);
  half8 h0 = { (_Float16)v0.x, (_Float16)v0.y, (_Float16)v0.z, (_Float16)v0.w,
               (_Float16)v1.x, (_Float16)v1.y, (_Float16)v1.z, (_Float16)v1.w };
  half8 h1 = { (_Float16)v2.x, (_Float16)v2.y, (_Float16)v2.z, (_Float16)v2.w,
               (_Float16)v3.x, (_Float16)v3.y, (_Float16)v3.z, (_Float16)v3.w };
  *(half8*)(xh + i) = h0;
  *(half8*)(xh + i + 8) = h1;
}

// --- prep part 2: v transpose + vsum + w/zero rows + arg zero --------------
// blocks [0,1024):     v[f][n] -> vt[n][f] fp16 transpose (64x64 tiles)
// blocks [1024,1536):  vsum rows vt[2048+k][f] = sum_s v[f][s*64+k]
// blocks [1536,2048):  w row (2112) + zero rows (2113..2175)
// blocks [2048,2112):  zero arg[16384]
__global__ __launch_bounds__(256) void k_prep_v(const float* __restrict__ v,
                                                const float* __restrict__ w,
                                                _Float16* __restrict__ vt,
                                                float* __restrict__ arg) {
  const int bb = blockIdx.x;
  const int t = threadIdx.x;
  if (bb < 1024) {
    __shared__ _Float16 tile[64 * 68];
    const int f0 = (bb >> 5) * 64;
    const int n0 = (bb & 31) * 64;
#pragma unroll
    for (int j = 0; j < 4; ++j) {
      int c = j * 256 + t;
      int row = c >> 4;                           // f local
      int col = (c & 15) * 4;                     // n local
      float4 val = *(const float4*)(v + (size_t)(f0 + row) * NCOLS + n0 + col);
      tile[row * 68 + col + 0] = (_Float16)val.x;
      tile[row * 68 + col + 1] = (_Float16)val.y;
      tile[row * 68 + col + 2] = (_Float16)val.z;
      tile[row * 68 + col + 3] = (_Float16)val.w;
    }
    __syncthreads();
#pragma unroll
    for (int j = 0; j < 4; ++j) {
      int c = j * 256 + t;
      int nl = c >> 4;                            // n local (row of vt)
      int fl = (c & 15) * 4;                      // f local group of 4
      half4 h = { tile[(fl + 0) * 68 + nl], tile[(fl + 1) * 68 + nl],
                  tile[(fl + 2) * 68 + nl], tile[(fl + 3) * 68 + nl] };
      *(half4*)(vt + (size_t)(n0 + nl) * FEAT + f0 + fl) = h;
    }
  } else if (bb < 1536) {
    const int k = t & 63;
    const int f = (bb - 1024) * 4 + (t >> 6);
    float s = 0.f;
#pragma unroll
    for (int si = 0; si < FIELD; ++si) s += v[(size_t)f * NCOLS + si * KDIM + k];
    vt[(size_t)(NCOLS + k) * FEAT + f] = (_Float16)s;
  } else if (bb < 2048) {
    int idx = (bb - 1536) * 256 + t;              // 64*2048 elements
    int r = NCOLS + KDIM + (idx >> 11);           // 2112..2175
    int f = idx & 2047;
    vt[(size_t)r * FEAT + f] = (r == NCOLS + KDIM) ? (_Float16)w[f] : (_Float16)0.f;
  } else {
    arg[(bb - 2048) * 256 + t] = 0.f;
  }
}

// --- fused GEMM + row-reduce epilogue: 256x256 tile, 8-wave ----------------
// R5 = R3 deep pipeline, K-SPLIT REMOVED (NT=32, full K per block).
//
// WHY R2/R3/R4 FAILED (post-mortem): the epilogue applies +-0.5*c^2 to each
// dot product c = sum_k A[m,k]*B[n,k]; squaring must happen AFTER the full-K
// sum. The K-split had two blocks each contributing 0.5*c_half^2, and
// c1^2 + c2^2 != (c1+c2)^2 -> deterministic absmax 468 across all three
// schedules. K-split is mathematically invalid here; the pipeline was fine.
//
// Pipeline (R3): register-fragment prefetch (read phase p+1's frags BEFORE
// phase p's MFMA; LDS drain hides under MFMA), ONE barrier per phase,
// explicit lgkmcnt(0) drains at end-ph0/end-ph2 (enforce the WAR invariant
// that segment re-stage never overlaps an in-flight ds_read; rule #18),
// counted vmcnt at phase ends (own-wave drain BEFORE the shared barrier).
//
// LDS: segA(buf,kg) = ((buf<<1)|kg)*8192 halves, segB = +32768. 128 KiB.
// Granule: 128 LDS-rows x 128B; (row,kc) at L=row&127,
//   slot=((row>>7)*4+kc)^(L&7) -> conflict-free ds_read_b128, linear
//   global_load_lds dest with pre-swizzled source.
//
// Stage schedule per iter t: ph0: A kg1(t+1)->buf^1   ph1: B kg1(t+1)->buf^1
//                            ph2: A kg0(t+2)->buf     ph3: B kg0(t+2)->buf
// Frag prefetch per phase (for the NEXT phase's MFMA):
//   ph0: afQ<-kg0 hi | ph1: afP,bf1<-kg1 | ph2: afQ<-kg1 hi | ph3: afP,bf0<-next kg0
// vmcnt: end-ph0 guards kg1(t) [6 newer in steady], end-ph2 guards kg0(t+1).
#define NT 32   // K-tiles per block: full K = 2048 / 64 (NO K-split)

#define VMCNT(N) asm volatile("s_waitcnt vmcnt(" #N ")" ::: "memory")
#define LGKM0()  asm volatile("s_waitcnt lgkmcnt(0)" ::: "memory")
#define SCHED0() __builtin_amdgcn_sched_barrier(0)
#define BARRIER() __builtin_amdgcn_s_barrier()
#define PRIO(N) __builtin_amdgcn_s_setprio(N)

__global__ __launch_bounds__(512, 2) void k_gemm(const _Float16* __restrict__ xh,
                                                 const _Float16* __restrict__ vt,
                                                 float* __restrict__ arg) {
  __shared__ __align__(16) _Float16 lds[65536];   // 128 KiB
  const int tid  = threadIdx.x;
  const int lane = tid & 63;
  const int wave = tid >> 6;      // 0..7
  const int wm   = wave >> 2;     // 0..1 -> M offset wm*128
  const int wn   = wave & 3;      // 0..3 -> N offset wn*64
  const int lr   = lane & 15;     // frag row (A) / col (B)
  const int q    = lane >> 4;     // k-chunk within 32-k granule

  // bijective XCD swizzle (576 = 8*72); m-fast within each XCD so
  // co-resident blocks on one XCD share the same B panel (L2-hot).
  const int bid = blockIdx.x;
  const int wg  = (bid & 7) * 72 + (bid >> 3);
  const int m0  = (wg & 63) * 256;
  const int n0  = (wg >> 6) * 256;               // 0..8

  // fragment LDS offsets (halves) within any granule segment.
  // offA[f]+4096 gives the high half (L jumps by 64, slot unchanged: 64&7==0).
  int offA[4], offB[4];
#pragma unroll
  for (int f = 0; f < 4; ++f) {
    int L = f * 16 + lr;
    int u = wm * 4 + q;
    offA[f] = L * 64 + ((u ^ (L & 7)) * 8);
  }
#pragma unroll
  for (int g = 0; g < 4; ++g) {
    int L = (wn & 1) * 64 + g * 16 + lr;
    int u = (wn >> 1) * 4 + q;
    offB[g] = L * 64 + ((u ^ (L & 7)) * 8);
  }

  // staging source decode: linear chunk tid -> (row, kc); dest+4096 -> row+64.
  const int L0   = tid >> 3;
  const int u0   = (tid & 7) ^ (L0 & 7);
  const int row0 = (u0 >> 2) * 128 + L0;
  const int kc0  = u0 & 3;
  const _Float16* pA0 = xh + (size_t)(m0 + row0) * FEAT + kc0 * 8;
  const _Float16* pA1 = pA0 + (size_t)64 * FEAT;
  const int rb0 = (n0 + row0      < NAUG) ? n0 + row0      : NAUG - 1;
  const int rb1 = (n0 + row0 + 64 < NAUG) ? n0 + row0 + 64 : NAUG - 1;
  const _Float16* pB0 = vt + (size_t)rb0 * FEAT + kc0 * 8;
  const _Float16* pB1 = vt + (size_t)rb1 * FEAT + kc0 * 8;

  auto stageA = [&](int koff, int seg) {
    load_lds16(pA0 + koff, lds + seg + tid * 8);
    load_lds16(pA1 + koff, lds + seg + 4096 + tid * 8);
  };
  auto stageB = [&](int koff, int seg) {
    load_lds16(pB0 + koff, lds + seg + tid * 8);
    load_lds16(pB1 + koff, lds + seg + 4096 + tid * 8);
  };

  floatx4 acc[8][4] = {};
  half8 afP[4], afQ[4], bf0[4], bf1[4];

  // prologue: kg0(0), kg1(0), kg0(1) in that exact issue order (12 loads).
  stageA(0, 0);       stageB(0, 32768);
  stageA(32, 8192);   stageB(32, 40960);
  stageA(64, 16384);  stageB(64, 49152);
  VMCNT(8);                      // own kg0(0) landed
  BARRIER();                     // -> everyone's kg0(0) landed
  SCHED0();
#pragma unroll
  for (int f = 0; f < 4; ++f) afP[f] = *(const half8*)(lds + offA[f]);
#pragma unroll
  for (int g = 0; g < 4; ++g) bf0[g] = *(const half8*)(lds + 32768 + offB[g]);

#pragma unroll 2
  for (int t = 0; t < NT; ++t) {
    const int sA0  = (t & 1) << 14;        // segA(buf, kg0)
    const int sA1  = sA0 + 8192;           // segA(buf, kg1)
    const int sB0  = 32768 + sA0;
    const int sB1  = sB0 + 8192;
    const int nsA0 = sA0 ^ 16384;          // segA(buf^1, kg0)
    const int nsA1 = nsA0 + 8192;
    const int nsB0 = 32768 + nsA0;
    const int nsB1 = nsB0 + 8192;

    // ---- ph0: MFMA kg0 x af-lo; prefetch afQ (kg0 hi); stage A kg1(t+1) ---
    BARRIER(); SCHED0();
#pragma unroll
    for (int f = 0; f < 4; ++f) afQ[f] = *(const half8*)(lds + sA0 + 4096 + offA[f]);
    if (t + 1 < NT) stageA((t + 1) * 64 + 32, nsA1);
    SCHED0(); PRIO(1);
#pragma unroll
    for (int f = 0; f < 4; ++f)
#pragma unroll
      for (int g = 0; g < 4; ++g)
        acc[f][g] = __builtin_amdgcn_mfma_f32_16x16x32_f16(afP[f], bf0[g],
                                                           acc[f][g], 0, 0, 0);
    PRIO(0); SCHED0();
    LGKM0();                               // own ph0 reads (sA0-hi) complete
    if (t < NT - 1) { VMCNT(6); } else { VMCNT(0); }   // kg1(t) landed (own)

    // ---- ph1: MFMA kg0 x af-hi; prefetch afP,bf1 (kg1); stage B kg1(t+1) --
    BARRIER(); SCHED0();
#pragma unroll
    for (int f = 0; f < 4; ++f) afP[f] = *(const half8*)(lds + sA1 + offA[f]);
#pragma unroll
    for (int g = 0; g < 4; ++g) bf1[g] = *(const half8*)(lds + sB1 + offB[g]);
    if (t + 1 < NT) stageB((t + 1) * 64 + 32, nsB1);
    SCHED0(); PRIO(1);
#pragma unroll
    for (int f = 0; f < 4; ++f)
#pragma unroll
      for (int g = 0; g < 4; ++g)
        acc[4 + f][g] = __builtin_amdgcn_mfma_f32_16x16x32_f16(afQ[f], bf0[g],
                                                               acc[4 + f][g], 0, 0, 0);
    PRIO(0); SCHED0();

    // ---- ph2: MFMA kg1 x af-lo; prefetch afQ (kg1 hi); stage A kg0(t+2) ---
    BARRIER(); SCHED0();
#pragma unroll
    for (int f = 0; f < 4; ++f) afQ[f] = *(const half8*)(lds + sA1 + 4096 + offA[f]);
    if (t + 2 < NT) stageA((t + 2) * 64, sA0);
    SCHED0(); PRIO(1);
#pragma unroll
    for (int f = 0; f < 4; ++f)
#pragma unroll
      for (int g = 0; g < 4; ++g)
        acc[f][g] = __builtin_amdgcn_mfma_f32_16x16x32_f16(afP[f], bf1[g],
                                                           acc[f][g], 0, 0, 0);
    PRIO(0); SCHED0();
    LGKM0();                               // own ph1+ph2 reads (sA1,sB1) complete
    if (t < NT - 2)       { VMCNT(6); }                 // kg0(t+1) landed (own)
    else if (t == NT - 2) { VMCNT(4); }

    // ---- ph3: MFMA kg1 x af-hi; prefetch afP,bf0 (next kg0); stage B ------
    BARRIER(); SCHED0();
    if (t + 1 < NT) {
#pragma unroll
      for (int f = 0; f < 4; ++f) afP[f] = *(const half8*)(lds + nsA0 + offA[f]);
#pragma unroll
      for (int g = 0; g < 4; ++g) bf0[g] = *(const half8*)(lds + nsB0 + offB[g]);
    }
    if (t + 2 < NT) stageB((t + 2) * 64, sB0);
    SCHED0(); PRIO(1);
#pragma unroll
    for (int f = 0; f < 4; ++f)
#pragma unroll
      for (int g = 0; g < 4; ++g)
        acc[4 + f][g] = __builtin_amdgcn_mfma_f32_16x16x32_f16(afQ[f], bf1[g],
                                                               acc[4 + f][g], 0, 0, 0);
    PRIO(0); SCHED0();
  }

  // Epilogue: C/D layout col=lane&15, row=(lane>>4)*4+reg.
  const int cq = lane >> 4;
  const int mrow = m0 + wm * 128;
  const int ncol = n0 + wn * 64;
#pragma unroll
  for (int f = 0; f < 8; ++f) {
#pragma unroll
    for (int r = 0; r < 4; ++r) {
      float contrib = 0.f;
#pragma unroll
      for (int g = 0; g < 4; ++g) {
        int col = ncol + g * 16 + lr;
        float vv = acc[f][g][r];
        float qv = vv * vv;
        if (col < NCOLS)                contrib -= 0.5f * qv;
        else if (col < NCOLS + KDIM)    contrib += 0.5f * qv;
        else if (col == NCOLS + KDIM)   contrib += vv;
      }
      contrib += __shfl_xor(contrib, 1);
      contrib += __shfl_xor(contrib, 2);
      contrib += __shfl_xor(contrib, 4);
      contrib += __shfl_xor(contrib, 8);
      if (lr == 0) atomicAdd(&arg[mrow + f * 16 + cq * 4 + r], contrib);
    }
  }
}

// --- finalize: sigmoid ------------------------------------------------------
__global__ __launch_bounds__(256) void k_fin(const float* __restrict__ arg,
                                             const float* __restrict__ b,
                                             float* __restrict__ out) {
  int i = blockIdx.x * 256 + threadIdx.x;
  float z = arg[i] + b[0];
  out[i] = 1.f / (1.f + __expf(-z));
}

extern "C" void kernel_launch(void* const* d_in, const int* in_sizes, int n_in,
                              void* d_out, int out_size, void* d_ws, size_t ws_size,
                              hipStream_t stream) {
  const float* x = (const float*)d_in[0];   // [16384, 2048]
  const float* w = (const float*)d_in[1];   // [2048]
  const float* b = (const float*)d_in[2];   // scalar
  const float* v = (const float*)d_in[3];   // [2048, 32, 64]
  float* out = (float*)d_out;               // [16384] fp32

  char* ws = (char*)d_ws;
  _Float16* xh  = (_Float16*)ws;                          // 67,108,864 B
  _Float16* vt  = (_Float16*)(ws + 67108864);             //  8,912,896 B
  float*    arg = (float*)(ws + 67108864 + 8912896);      //     65,536 B

  k_prep_x<<<8192, 256, 0, stream>>>(x, xh);
  k_prep_v<<<2112, 256, 0, stream>>>(v, w, vt, arg);
  k_gemm<<<576, 512, 0, stream>>>(xh, vt, arg);
  k_fin<<<64, 256, 0, stream>>>(arg, b, out);
}

// Round 6
// 395.584 us; speedup vs baseline: 1.6431x; 1.6431x over previous
//
#include <hip/hip_runtime.h>
#include <cstdint>
#include <cstddef>

// Problem constants
#define B_ROWS 16384
#define FEAT   2048
#define FIELD  32
#define KDIM   64
#define NCOLS  2048           // FIELD*KDIM (main quadratic columns)
#define NAUG   2176           // 2048 + 64 (vsum) + 1 (w) + 63 zero-pad = 17*128

using half8   = __attribute__((ext_vector_type(8))) _Float16;
using half4   = __attribute__((ext_vector_type(4))) _Float16;
using floatx4 = __attribute__((ext_vector_type(4))) float;

// Async global->LDS, 16B per lane. LDS dest must be wave-uniform base + lane*16.
__device__ __forceinline__ void load_lds16(const void* g, void* l) {
  __builtin_amdgcn_global_load_lds((const __attribute__((address_space(1))) void*)g,
                                   (__attribute__((address_space(3))) void*)l, 16, 0, 0);
}

// --- prep part 1: x fp32 -> xh fp16 ----------------------------------------
__global__ __launch_bounds__(256) void k_prep_x(const float* __restrict__ x,
                                                _Float16* __restrict__ xh) {
  const int bb = blockIdx.x;
  const int t = threadIdx.x;
  size_t i = ((size_t)bb * 256 + t) * 16;
  float4 v0 = *(const float4*)(x + i);
  float4 v1 = *(const float4*)(x + i + 4);
  float4 v2 = *(const float4*)(x + i + 8);
  float4 v3 = *(const float4*)(x + i + 12);
  half8 h0 = { (_Float16)v0.x, (_Float16)v0.y, (_Float16)v0.z, (_Float16)v0.w,
               (_Float16)v1.x, (_Float16)v1.y, (_Float16)v1.z, (_Float16)v1.w };
  half8 h1 = { (_Float16)v2.x, (_Float16)v2.y, (_Float16)v2.z, (_Float16)v2.w,
               (_Float16)v3.x, (_Float16)v3.y, (_Float16)v3.z, (_Float16)v3.w };
  *(half8*)(xh + i) = h0;
  *(half8*)(xh + i + 8) = h1;
}

// --- prep part 2: v transpose + vsum + w/zero rows + arg zero --------------
__global__ __launch_bounds__(256) void k_prep_v(const float* __restrict__ v,
                                                const float* __restrict__ w,
                                                _Float16* __restrict__ vt,
                                                float* __restrict__ arg) {
  const int bb = blockIdx.x;
  const int t = threadIdx.x;
  if (bb < 1024) {
    __shared__ _Float16 tile[64 * 68];
    const int f0 = (bb >> 5) * 64;
    const int n0 = (bb & 31) * 64;
#pragma unroll
    for (int j = 0; j < 4; ++j) {
      int c = j * 256 + t;
      int row = c >> 4;                           // f local
      int col = (c & 15) * 4;                     // n local
      float4 val = *(const float4*)(v + (size_t)(f0 + row) * NCOLS + n0 + col);
      tile[row * 68 + col + 0] = (_Float16)val.x;
      tile[row * 68 + col + 1] = (_Float16)val.y;
      tile[row * 68 + col + 2] = (_Float16)val.z;
      tile[row * 68 + col + 3] = (_Float16)val.w;
    }
    __syncthreads();
#pragma unroll
    for (int j = 0; j < 4; ++j) {
      int c = j * 256 + t;
      int nl = c >> 4;                            // n local (row of vt)
      int fl = (c & 15) * 4;                      // f local group of 4
      half4 h = { tile[(fl + 0) * 68 + nl], tile[(fl + 1) * 68 + nl],
                  tile[(fl + 2) * 68 + nl], tile[(fl + 3) * 68 + nl] };
      *(half4*)(vt + (size_t)(n0 + nl) * FEAT + f0 + fl) = h;
    }
  } else if (bb < 1536) {
    const int k = t & 63;
    const int f = (bb - 1024) * 4 + (t >> 6);
    float s = 0.f;
#pragma unroll
    for (int si = 0; si < FIELD; ++si) s += v[(size_t)f * NCOLS + si * KDIM + k];
    vt[(size_t)(NCOLS + k) * FEAT + f] = (_Float16)s;
  } else if (bb < 2048) {
    int idx = (bb - 1536) * 256 + t;              // 64*2048 elements
    int r = NCOLS + KDIM + (idx >> 11);           // 2112..2175
    int f = idx & 2047;
    vt[(size_t)r * FEAT + f] = (r == NCOLS + KDIM) ? (_Float16)w[f] : (_Float16)0.f;
  } else {
    arg[(bb - 2048) * 256 + t] = 0.f;
  }
}

// --- fused GEMM + row-reduce epilogue: 256x256 tile, 8-wave, 8-phase -------
// R6 = the VERIFIED R1 schedule (213us, passed), verbatim, with ONLY the
// grid decode changed to a 3-n-chunk XCD mapping.
//
// Fetch-locality model (from R1=310MB vs R5=600MB FETCH evidence): the
// reusable operand is the panel consecutive same-XCD blocks SHARE. m-fast
// gave each XCD 64 distinct A panels (streams all 67MB of xh through its
// 4MB L2; only B hot). New mapping: wg = ng*192 + mi*3 + nr (ng=n-group of
// 3, mi=m index, nr=n within group) -> each XCD holds ~3 B panels (3MB,
// L2-RESIDENT across all its m rows) and each A panel is fetched once,
// consumed by its 3 temporally-adjacent n-neighbors while L2-hot.
// Expected TCC fetch ~ 67MB(A once per disjoint m-range) + B refills.
//
// Pipeline (verified R1): 4 phases/K-tile, 16 MFMA each; per phase
// {ds-read frags; stage one granule; barrier; lgkmcnt(0); setprio(1);
// MFMA; setprio(0); barrier}; ONE counted vmcnt(4) per K-tile at ph3 end
// (kg1(t+1)&kg0(t+2) remain in flight), vmcnt(0) at the tail.
// LDS: segA(buf,kg) = ((buf<<1)|kg)*8192 halves, segB = +32768. 128 KiB.
// Granule: 128 LDS-rows x 128B; (row,kc) at L=row&127,
//   slot=((row>>7)*4+kc)^(L&7): conflict-free ds_read_b128, linear
//   global_load_lds dest with pre-swizzled source.
__global__ __launch_bounds__(512, 2) void k_gemm(const _Float16* __restrict__ xh,
                                                 const _Float16* __restrict__ vt,
                                                 float* __restrict__ arg) {
  __shared__ __align__(16) _Float16 lds[65536];   // 128 KiB
  const int tid  = threadIdx.x;
  const int lane = tid & 63;
  const int wave = tid >> 6;      // 0..7
  const int wm   = wave >> 2;     // 0..1 -> M offset wm*128
  const int wn   = wave & 3;      // 0..3 -> N offset wn*64
  const int lr   = lane & 15;     // frag row (A) / col (B)
  const int q    = lane >> 4;     // k-chunk within 32-k granule

  // XCD swizzle (576 = 8*72, bijective) + 3-n-chunk decode:
  // wg = ng*192 + mi*3 + nr;  n = ng*3 + nr, m = mi.
  const int bid = blockIdx.x;
  const int wg  = (bid & 7) * 72 + (bid >> 3);
  const int ng  = wg / 192;
  const int rem = wg - ng * 192;
  const int mi  = rem / 3;
  const int nr  = rem - mi * 3;
  const int m0  = mi * 256;
  const int n0  = (ng * 3 + nr) * 256;           // 0..2048

  // fragment LDS offsets (halves) within any granule segment.
  // offA[f]+4096 gives the high half (L jumps by 64, slot unchanged: 64&7==0).
  int offA[4], offB[4];
#pragma unroll
  for (int f = 0; f < 4; ++f) {
    int L = f * 16 + lr;
    int u = wm * 4 + q;
    offA[f] = L * 64 + ((u ^ (L & 7)) * 8);
  }
#pragma unroll
  for (int g = 0; g < 4; ++g) {
    int L = (wn & 1) * 64 + g * 16 + lr;
    int u = (wn >> 1) * 4 + q;
    offB[g] = L * 64 + ((u ^ (L & 7)) * 8);
  }

  // staging source decode: linear chunk tid -> (row, kc); dest+4096 -> row+64.
  const int L0   = tid >> 3;
  const int u0   = (tid & 7) ^ (L0 & 7);
  const int row0 = (u0 >> 2) * 128 + L0;
  const int kc0  = u0 & 3;
  const _Float16* pA0 = xh + (size_t)(m0 + row0) * FEAT + kc0 * 8;
  const _Float16* pA1 = pA0 + (size_t)64 * FEAT;
  const int rb0 = (n0 + row0      < NAUG) ? n0 + row0      : NAUG - 1;
  const int rb1 = (n0 + row0 + 64 < NAUG) ? n0 + row0 + 64 : NAUG - 1;
  const _Float16* pB0 = vt + (size_t)rb0 * FEAT + kc0 * 8;
  const _Float16* pB1 = vt + (size_t)rb1 * FEAT + kc0 * 8;

  auto stageA = [&](int koff, int seg) {
    load_lds16(pA0 + koff, lds + seg + tid * 8);
    load_lds16(pA1 + koff, lds + seg + 4096 + tid * 8);
  };
  auto stageB = [&](int koff, int seg) {
    load_lds16(pB0 + koff, lds + seg + tid * 8);
    load_lds16(pB1 + koff, lds + seg + 4096 + tid * 8);
  };

  floatx4 acc[8][4] = {};
  half8 af[4], bf[4];

  // prologue: K-tile 0 (both granules) + K-tile 1 kg0.
  stageA(0, 0);       stageB(0, 32768);
  stageA(32, 8192);   stageB(32, 40960);
  stageA(64, 16384);  stageB(64, 49152);
  asm volatile("s_waitcnt vmcnt(4)" ::: "memory");  // K-tile 0 fully landed
  __builtin_amdgcn_s_barrier();

#define PHASE_TAIL()                                        \
    __builtin_amdgcn_s_barrier();                           \
    asm volatile("s_waitcnt lgkmcnt(0)" ::: "memory");      \
    __builtin_amdgcn_sched_barrier(0);                      \
    __builtin_amdgcn_s_setprio(1)

#define PHASE_END()                                         \
    __builtin_amdgcn_s_setprio(0);                          \
    __builtin_amdgcn_s_barrier()

#pragma unroll 2
  for (int t = 0; t < 32; ++t) {
    const int sA0  = ((t & 1) << 1) * 8192;                 // segA(buf, kg0)
    const int sB0  = 32768 + sA0;                           // segB(buf, kg0)
    const int sPA1 = ((((t + 1) & 1) << 1) | 1) * 8192;     // segA(buf^1, kg1)

    // ---- phase 0: ks=0, M-frags 0-3 ---------------------------------------
#pragma unroll
    for (int g = 0; g < 4; ++g) bf[g] = *(const half8*)(lds + sB0 + offB[g]);
#pragma unroll
    for (int f = 0; f < 4; ++f) af[f] = *(const half8*)(lds + sA0 + offA[f]);
    if (t < 31) stageA((t + 1) * 64 + 32, sPA1);
    PHASE_TAIL();
#pragma unroll
    for (int f = 0; f < 4; ++f)
#pragma unroll
      for (int g = 0; g < 4; ++g)
        acc[f][g] = __builtin_amdgcn_mfma_f32_16x16x32_f16(af[f], bf[g],
                                                           acc[f][g], 0, 0, 0);
    PHASE_END();

    // ---- phase 1: ks=0, M-frags 4-7 (bf reused) ---------------------------
#pragma unroll
    for (int f = 0; f < 4; ++f) af[f] = *(const half8*)(lds + sA0 + 4096 + offA[f]);
    if (t < 31) stageB((t + 1) * 64 + 32, 32768 + sPA1);
    PHASE_TAIL();
#pragma unroll
    for (int f = 0; f < 4; ++f)
#pragma unroll
      for (int g = 0; g < 4; ++g)
        acc[4 + f][g] = __builtin_amdgcn_mfma_f32_16x16x32_f16(af[f], bf[g],
                                                               acc[4 + f][g], 0, 0, 0);
    PHASE_END();

    // ---- phase 2: ks=32, M-frags 0-3 --------------------------------------
#pragma unroll
    for (int g = 0; g < 4; ++g) bf[g] = *(const half8*)(lds + sB0 + 8192 + offB[g]);
#pragma unroll
    for (int f = 0; f < 4; ++f) af[f] = *(const half8*)(lds + sA0 + 8192 + offA[f]);
    if (t < 30) stageA((t + 2) * 64, sA0);
    PHASE_TAIL();
#pragma unroll
    for (int f = 0; f < 4; ++f)
#pragma unroll
      for (int g = 0; g < 4; ++g)
        acc[f][g] = __builtin_amdgcn_mfma_f32_16x16x32_f16(af[f], bf[g],
                                                           acc[f][g], 0, 0, 0);
    PHASE_END();

    // ---- phase 3: ks=32, M-frags 4-7 + per-K-tile counted vmcnt -----------
#pragma unroll
    for (int f = 0; f < 4; ++f) af[f] = *(const half8*)(lds + sA0 + 12288 + offA[f]);
    if (t < 30) stageB((t + 2) * 64, sB0);
    __builtin_amdgcn_s_barrier();
    asm volatile("s_waitcnt lgkmcnt(0)" ::: "memory");
    __builtin_amdgcn_sched_barrier(0);
    __builtin_amdgcn_s_setprio(1);
#pragma unroll
    for (int f = 0; f < 4; ++f)
#pragma unroll
      for (int g = 0; g < 4; ++g)
        acc[4 + f][g] = __builtin_amdgcn_mfma_f32_16x16x32_f16(af[f], bf[g],
                                                               acc[4 + f][g], 0, 0, 0);
    __builtin_amdgcn_s_setprio(0);
    // steady state: kg1(t+1)+kg0(t+2) (4 loads) remain in flight across the
    // boundary; vmcnt(4) drains kg1(t)'s 4 loads. Tail: drain fully.
    if (t < 30) { asm volatile("s_waitcnt vmcnt(4)" ::: "memory"); }
    else        { asm volatile("s_waitcnt vmcnt(0)" ::: "memory"); }
    __builtin_amdgcn_sched_barrier(0);
    __builtin_amdgcn_s_barrier();
  }
#undef PHASE_TAIL
#undef PHASE_END

  // Epilogue: C/D layout col=lane&15, row=(lane>>4)*4+reg.
  const int cq = lane >> 4;
  const int mrow = m0 + wm * 128;
  const int ncol = n0 + wn * 64;
#pragma unroll
  for (int f = 0; f < 8; ++f) {
#pragma unroll
    for (int r = 0; r < 4; ++r) {
      float contrib = 0.f;
#pragma unroll
      for (int g = 0; g < 4; ++g) {
        int col = ncol + g * 16 + lr;
        float vv = acc[f][g][r];
        float qv = vv * vv;
        if (col < NCOLS)                contrib -= 0.5f * qv;
        else if (col < NCOLS + KDIM)    contrib += 0.5f * qv;
        else if (col == NCOLS + KDIM)   contrib += vv;
      }
      contrib += __shfl_xor(contrib, 1);
      contrib += __shfl_xor(contrib, 2);
      contrib += __shfl_xor(contrib, 4);
      contrib += __shfl_xor(contrib, 8);
      if (lr == 0) atomicAdd(&arg[mrow + f * 16 + cq * 4 + r], contrib);
    }
  }
}

// --- finalize: sigmoid ------------------------------------------------------
__global__ __launch_bounds__(256) void k_fin(const float* __restrict__ arg,
                                             const float* __restrict__ b,
                                             float* __restrict__ out) {
  int i = blockIdx.x * 256 + threadIdx.x;
  float z = arg[i] + b[0];
  out[i] = 1.f / (1.f + __expf(-z));
}

extern "C" void kernel_launch(void* const* d_in, const int* in_sizes, int n_in,
                              void* d_out, int out_size, void* d_ws, size_t ws_size,
                              hipStream_t stream) {
  const float* x = (const float*)d_in[0];   // [16384, 2048]
  const float* w = (const float*)d_in[1];   // [2048]
  const float* b = (const float*)d_in[2];   // scalar
  const float* v = (const float*)d_in[3];   // [2048, 32, 64]
  float* out = (float*)d_out;               // [16384] fp32

  char* ws = (char*)d_ws;
  _Float16* xh  = (_Float16*)ws;                          // 67,108,864 B
  _Float16* vt  = (_Float16*)(ws + 67108864);             //  8,912,896 B
  float*    arg = (float*)(ws + 67108864 + 8912896);      //     65,536 B

  k_prep_x<<<8192, 256, 0, stream>>>(x, xh);
  k_prep_v<<<2112, 256, 0, stream>>>(v, w, vt, arg);
  k_gemm<<<576, 512, 0, stream>>>(xh, vt, arg);
  k_fin<<<64, 256, 0, stream>>>(arg, b, out);
}